// Round 13
// baseline (1422.151 us; speedup 1.0000x reference)
//
#include <hip/hip_runtime.h>
#include <hip/hip_bf16.h>
#include <hip/hip_fp16.h>
#include <math.h>

#define EPSV 1e-5f

typedef short short8 __attribute__((ext_vector_type(8)));
typedef float f32x4 __attribute__((ext_vector_type(4)));
typedef unsigned long long u64;

#define MFMA(a, b, c) __builtin_amdgcn_mfma_f32_16x16x32_f16(a, b, c, 0, 0, 0)

// ---------------- ws layout (bytes) ----------------
#define OFF_SC1    8192            // 64 f32
#define OFF_SH1    8448
#define OFF_SC2    8704            // 128 f32
#define OFF_SH2    9216
#define OFF_B0     9728            // 1024 f32 = 4096
#define OFF_B1     13824           // 4096
#define OFF_PART1  17920           // 256*64*2*4 = 131072
#define OFF_PART2  148992          // 256*128*2*4 = 262144
#define OFF_W2F    411136          // 40960 f16 = 81920
#define OFF_WF     493056          // 917504 f16 = 1835008
#define OFF_SEQ    2328064         // 256*256*128*2 = 16777216 (f16 [b][t][c])
#define OFF_H0W    19105280        // 2*16*128*16*8 = 524288 (tagged u64, depth-2)
#define OFF_H1W    19629568        // 3*16*128*16*8 = 786432 (depth-3)
#define OFF_HF     20416000        // 256*256*4 = 262144 (f32)
// end 20,678,144

__device__ __forceinline__ unsigned short f2h(float f) {
  return __half_as_ushort(__float2half(f));
}
__device__ __forceinline__ float h2f(unsigned short u) {
  return __half2float(__ushort_as_half(u));
}
__device__ __forceinline__ float sigf(float x) { return 1.f / (1.f + __expf(-x)); }
__device__ __forceinline__ float tanhfast(float x) {
  return 1.f - 2.f / (__expf(2.f * x) + 1.f);
}

// ---------------- init: zero tagged h word buffers (1.25 MB) ----------------
__global__ void k_init(u64* hz) {
  int i = blockIdx.x * 256 + threadIdx.x;  // grid 640 -> 163840 u64
  if (i < 163840) hz[i] = 0ULL;
}

// ---------------- conv1 + relu + pool4, BN1 partial stats ----------------
__global__ __launch_bounds__(256, 2) void k_conv1(const float* __restrict__ x,
                                                  const float* __restrict__ w1,
                                                  const float* __restrict__ b1,
                                                  float* __restrict__ part1) {
  __shared__ float xs[4104];
  __shared__ float w1s[576];
  __shared__ float b1s[64];
  __shared__ float red[64][4][2];
  const int tid = threadIdx.x, b = blockIdx.x;
  for (int j = tid; j < 4104; j += 256) {
    int p = j - 4;
    xs[j] = (p >= 0 && p < 4096) ? x[b * 4096 + p] : 0.f;
  }
  for (int j = tid; j < 576; j += 256) w1s[j] = w1[j];
  if (tid < 64) b1s[tid] = b1[tid];
  __syncthreads();
  const int c = tid >> 2, lq = tid & 3;
  float wr[9];
#pragma unroll
  for (int k = 0; k < 9; k++) wr[k] = w1s[c * 9 + k];
  const float bb = b1s[c];
  float S = 0.f, SS = 0.f;
  for (int li = 0; li < 256; li++) {
    int l = lq * 256 + li;
    int base = 4 * l;
    float a4 = 0.f;
#pragma unroll
    for (int jj = 0; jj < 4; jj++) {
      float cv = bb;
#pragma unroll
      for (int k = 0; k < 9; k++) cv += xs[base + jj + k] * wr[k];
      a4 += fmaxf(cv, 0.f);
    }
    float y = 0.25f * a4;
    S += y;
    SS += y * y;
  }
  red[c][lq][0] = S;
  red[c][lq][1] = SS;
  __syncthreads();
  if (tid < 64) {
    float s = 0.f, ss = 0.f;
#pragma unroll
    for (int q = 0; q < 4; q++) {
      s += red[tid][q][0];
      ss += red[tid][q][1];
    }
    part1[(b * 64 + tid) * 2 + 0] = s;
    part1[(b * 64 + tid) * 2 + 1] = ss;
  }
}

// ---------------- BN1 finalize ----------------
__global__ void k_bn1(const float* __restrict__ part1, const float* __restrict__ g,
                      const float* __restrict__ bt, float* __restrict__ sc,
                      float* __restrict__ sh) {
  __shared__ float rs[256], rss[256];
  const int c = blockIdx.x, tid = threadIdx.x;
  rs[tid] = part1[(tid * 64 + c) * 2 + 0];
  rss[tid] = part1[(tid * 64 + c) * 2 + 1];
  __syncthreads();
  for (int st = 128; st > 0; st >>= 1) {
    if (tid < st) {
      rs[tid] += rs[tid + st];
      rss[tid] += rss[tid + st];
    }
    __syncthreads();
  }
  if (tid == 0) {
    const float N = 256.f * 1024.f;
    float mean = rs[0] / N;
    float var = rss[0] / N - mean * mean;
    float scale = g[c] * rsqrtf(var + EPSV);
    sc[c] = scale;
    sh[c] = bt[c] - mean * scale;
  }
}

// ---------------- w2 -> MFMA B-fragment layout (f16) ----------------
__global__ void k_w2frag(const float* __restrict__ w2,
                         unsigned short* __restrict__ w2f) {
  int n = blockIdx.x * 256 + threadIdx.x;  // < 40960
  if (n >= 40960) return;
  int e = n & 7, lane = (n >> 3) & 63, ot = (n >> 9) & 7, sc = n >> 12;
  int s = sc >> 1, c2 = sc & 1;
  int o = ot * 16 + (lane & 15);
  int i = c2 * 32 + ((lane >> 4) << 3) + e;
  w2f[n] = f2h(w2[o * 320 + i * 5 + s]);
}

// ---------------- conv2 via MFMA (recomputes conv1+bn1 into LDS y1t) -------
__global__ __launch_bounds__(256, 1) void k_conv2(
    const float* __restrict__ x, const float* __restrict__ w1,
    const float* __restrict__ b1, const float* __restrict__ sc1,
    const float* __restrict__ sh1, const unsigned short* __restrict__ w2f,
    const float* __restrict__ b2, unsigned short* __restrict__ seq,
    float* __restrict__ part2) {
  __shared__ float xs[4104];
  __shared__ unsigned short y1t[1028][66];  // row = l+2, col = i
  __shared__ float w1s[576], b1s[64], s1s[64], h1s[64], b2s[128];
  __shared__ float red[4][2][128];
  const int tid = threadIdx.x, b = blockIdx.x;
  for (int j = tid; j < 4104; j += 256) {
    int p = j - 4;
    xs[j] = (p >= 0 && p < 4096) ? x[b * 4096 + p] : 0.f;
  }
  for (int j = tid; j < 576; j += 256) w1s[j] = w1[j];
  if (tid < 64) {
    b1s[tid] = b1[tid];
    s1s[tid] = sc1[tid];
    h1s[tid] = sh1[tid];
  }
  if (tid < 128) b2s[tid] = b2[tid];
  if (tid < 132) {
    int r4 = tid / 33, c4 = tid % 33;
    int row = (r4 < 2) ? r4 : (1024 + r4);
    ((unsigned int*)&y1t[row][0])[c4] = 0u;
  }
  __syncthreads();
  {
    const int i2 = tid & 31, lg = tid >> 5;
    const int ia = 2 * i2, ib = ia + 1;
    float wra[9], wrb[9];
#pragma unroll
    for (int k = 0; k < 9; k++) {
      wra[k] = w1s[ia * 9 + k];
      wrb[k] = w1s[ib * 9 + k];
    }
    const float bia = b1s[ia], bib = b1s[ib];
    const float sa = s1s[ia], sb = s1s[ib], ha = h1s[ia], hb = h1s[ib];
    for (int j = 0; j < 128; j++) {
      int l = lg * 128 + j;
      float xv[12];
#pragma unroll
      for (int m = 0; m < 12; m++) xv[m] = xs[4 * l + m];
      float aa = 0.f, ab = 0.f;
#pragma unroll
      for (int jj = 0; jj < 4; jj++) {
        float ca = bia, cb = bib;
#pragma unroll
        for (int k = 0; k < 9; k++) {
          float xx = xv[jj + k];
          ca += xx * wra[k];
          cb += xx * wrb[k];
        }
        aa += fmaxf(ca, 0.f);
        ab += fmaxf(cb, 0.f);
      }
      float va = 0.25f * aa * sa + ha;
      float vb = 0.25f * ab * sb + hb;
      unsigned int pk = (unsigned int)f2h(va) | ((unsigned int)f2h(vb) << 16);
      *(unsigned int*)&y1t[l + 2][ia] = pk;
    }
  }
  __syncthreads();
  const int wv = tid >> 6, lane = tid & 63;
  const int colo = lane & 15, rq = lane >> 4;
  float Sa[2][4], SSa[2][4];
#pragma unroll
  for (int a = 0; a < 2; a++)
#pragma unroll
    for (int c = 0; c < 4; c++) {
      Sa[a][c] = 0.f;
      SSa[a][c] = 0.f;
    }
#pragma unroll
  for (int og = 0; og < 2; og++) {
    short8 bf[4][10];
#pragma unroll
    for (int ot = 0; ot < 4; ot++)
#pragma unroll
      for (int sc = 0; sc < 10; sc++)
        bf[ot][sc] = *(const short8*)(w2f + ((sc * 8 + og * 4 + ot) * 64 + lane) * 8);
    for (int ltw = 0; ltw < 16; ltw++) {
      int lt = wv * 16 + ltw;
      int lbase = lt * 16;
      short8 af[10];
#pragma unroll
      for (int s = 0; s < 5; s++)
#pragma unroll
        for (int c2 = 0; c2 < 2; c2++)
          af[s * 2 + c2] =
              *(const short8*)&y1t[lbase + colo + s][c2 * 32 + rq * 8];
#pragma unroll
      for (int ot = 0; ot < 4; ot++) {
        f32x4 acc = {0.f, 0.f, 0.f, 0.f};
#pragma unroll
        for (int sc = 0; sc < 10; sc++)
          acc = MFMA(af[sc], bf[ot][sc], acc);
        int o = (og * 4 + ot) * 16 + colo;
        float bv = b2s[o];
        float s4 = fmaxf(acc[0] + bv, 0.f) + fmaxf(acc[1] + bv, 0.f) +
                   fmaxf(acc[2] + bv, 0.f) + fmaxf(acc[3] + bv, 0.f);
        float y = 0.25f * s4;
        int t_out = lt * 4 + rq;
        seq[(b * 256 + t_out) * 128 + o] = f2h(y);
        Sa[og][ot] += y;
        SSa[og][ot] += y * y;
      }
    }
  }
#pragma unroll
  for (int og = 0; og < 2; og++)
#pragma unroll
    for (int ot = 0; ot < 4; ot++) {
      float sv = Sa[og][ot], ssv = SSa[og][ot];
      sv += __shfl_xor(sv, 16, 64);
      sv += __shfl_xor(sv, 32, 64);
      ssv += __shfl_xor(ssv, 16, 64);
      ssv += __shfl_xor(ssv, 32, 64);
      if (rq == 0) {
        int o = (og * 4 + ot) * 16 + colo;
        red[wv][0][o] = sv;
        red[wv][1][o] = ssv;
      }
    }
  __syncthreads();
  if (tid < 128) {
    float s = red[0][0][tid] + red[1][0][tid] + red[2][0][tid] + red[3][0][tid];
    float ss = red[0][1][tid] + red[1][1][tid] + red[2][1][tid] + red[3][1][tid];
    part2[(b * 128 + tid) * 2 + 0] = s;
    part2[(b * 128 + tid) * 2 + 1] = ss;
  }
}

// ---------------- BN2 finalize ----------------
__global__ void k_bn2(const float* __restrict__ part2, const float* __restrict__ g,
                      const float* __restrict__ bt, float* __restrict__ sc,
                      float* __restrict__ sh) {
  __shared__ float rs[256], rss[256];
  const int o = blockIdx.x, tid = threadIdx.x;
  rs[tid] = part2[(tid * 128 + o) * 2 + 0];
  rss[tid] = part2[(tid * 128 + o) * 2 + 1];
  __syncthreads();
  for (int st = 128; st > 0; st >>= 1) {
    if (tid < st) {
      rs[tid] += rs[tid + st];
      rss[tid] += rss[tid + st];
    }
    __syncthreads();
  }
  if (tid == 0) {
    const float N = 65536.f;
    float mean = rs[0] / N;
    float var = rss[0] / N - mean * mean;
    float scale = g[o] * rsqrtf(var + EPSV);
    sc[o] = scale;
    sh[o] = bt[o] - mean * scale;
  }
}

// ---------------- fold BN2 shift into layer-0 bias ----------------
__global__ void k_bias(const float* __restrict__ bi0, const float* __restrict__ bh0,
                       const float* __restrict__ wi0, const float* __restrict__ sh2,
                       const float* __restrict__ bi1, const float* __restrict__ bh1,
                       float* __restrict__ b0arr, float* __restrict__ b1arr) {
  int g = blockIdx.x * 256 + threadIdx.x;  // < 1024
  float s = bi0[g] + bh0[g];
  for (int k = 0; k < 128; k++) s += sh2[k] * wi0[k * 1024 + g];
  b0arr[g] = s;
  b1arr[g] = bi1[g] + bh1[g];
}

// ---------------- LSTM weights -> A-fragment layout (f16, BN2-scaled) -------
__global__ void k_wfrag(const float* __restrict__ wi0, const float* __restrict__ wh0,
                        const float* __restrict__ wi1, const float* __restrict__ wh1,
                        const float* __restrict__ sc2,
                        unsigned short* __restrict__ wf) {
  const int slot = blockIdx.x / 56;
  const int idx = (blockIdx.x % 56) * 256 + threadIdx.x;  // < 14336
  const int j = idx >> 9, lane = (idx >> 3) & 63, e = idx & 7;
  const int sh = slot >> 2, wv = slot & 3;
  const int m = lane & 15;
  const int gcol = (m & 3) * 256 + sh * 16 + wv * 4 + (m >> 2);
  float v;
  if (j < 12) {
    int k = j * 32 + ((lane >> 4) << 3) + e;
    v = (k < 128) ? sc2[k] * wi0[k * 1024 + gcol] : wh0[(k - 128) * 1024 + gcol];
  } else {
    int k = (j - 12) * 32 + ((lane >> 4) << 3) + e;
    v = (k < 256) ? wi1[k * 1024 + gcol] : wh1[(k - 256) * 1024 + gcol];
  }
  wf[slot * 14336 + idx] = f2h(v);
}

// ---------------- persistent 2-layer LSTM, dual-chain per wave -------------
// grid 128: gp = blockIdx&7, sh = blockIdx>>3. Chains: gA=gp, gB=gp+8.
// Each wave runs BOTH groups' recurrences; weights (group-independent) are
// read once per iteration and feed both chains' MFMAs. h0: depth-2 tagged
// ping-pong, LDS-staged. h1: depth-3, direct fragment loads (no LDS/barrier).
// word = [tag:16 | h(2p):16 | h(2p+1):16 | 0:16], layout [buf][g][pair][batch]
__global__ __launch_bounds__(256, 1) void k_lstm(
    const unsigned short* __restrict__ seq, const unsigned short* __restrict__ wf,
    const float* __restrict__ b0arr, const float* __restrict__ b1arr,
    u64* __restrict__ h0w, u64* __restrict__ h1w, float* __restrict__ hfinal) {
  __shared__ unsigned short wlds[4 * 28 * 64 * 8];  // 114688 B
  __shared__ unsigned short hsA[2][16 * 264];       // 16896 B
  __shared__ unsigned short hsB[2][16 * 264];       // 16896 B
  const int tid = threadIdx.x;
  const int gp = blockIdx.x & 7, sh = blockIdx.x >> 3;
  const int gA = gp, gB = gp + 8;
  const int b0A = gA * 16, b0B = gB * 16;
  const int wv = tid >> 6, lane = tid & 63;
  const int bt = lane & 15;   // batch-local (B-frag col / D col)
  const int ul = lane >> 4;   // unit-local (D row quad / B-frag k-quad)
  const int q8 = ul * 8;

  // ---- stage weight A-fragments into LDS (one copy, fragment-ordered) ----
  {
    const u64* src = (const u64*)(wf + sh * 4 * 14336);
    u64* dst = (u64*)wlds;
    for (int j = tid; j < 14336; j += 256) dst[j] = src[j];
  }
#define LW(j) (*(const short8*)&wlds[(((wv)*28 + (j)) * 64 + lane) * 8])

  f32x4 b0v, b1v;
#pragma unroll
  for (int r = 0; r < 4; r++) {
    int gcol = r * 256 + sh * 16 + wv * 4 + ul;
    b0v[r] = b0arr[gcol];
    b1v[r] = b1arr[gcol];
  }
  float c0A = 0.f, c1A = 0.f, h1vA = 0.f;
  float c0B = 0.f, c1B = 0.f, h1vB = 0.f;
  const int pidx = (sh * 8 + wv * 2 + (ul >> 1)) * 16 + bt;
  u64* const st0A = h0w + gA * 2048 + pidx;
  u64* const st0B = h0w + gB * 2048 + pidx;
  u64* const st1A = h1w + gA * 2048 + pidx;
  u64* const st1B = h1w + gB * 2048 + pidx;
  const int fw0 = (ul * 4) * 16 + bt;  // h1 fragment-word base
  __syncthreads();  // weights staged

  // --- prologue: h0(0) = cell(x(0), c=0) for both chains; tag 1, buf 0 ---
  {
    const unsigned short* xpA = seq + ((b0A + bt) * 256 + 0) * 128 + q8;
    const unsigned short* xpB = seq + ((b0B + bt) * 256 + 0) * 128 + q8;
    short8 xaA[4], xaB[4];
#pragma unroll
    for (int m = 0; m < 4; m++) {
      xaA[m] = *(const short8*)(xpA + m * 32);
      xaB[m] = *(const short8*)(xpB + m * 32);
    }
    f32x4 accA = b0v, accB = b0v;
#pragma unroll
    for (int m = 0; m < 4; m++) {
      short8 lw = LW(m);
      accA = MFMA(lw, xaA[m], accA);
      accB = MFMA(lw, xaB[m], accB);
    }
    c0A = sigf(accA[1]) * c0A + sigf(accA[0]) * tanhfast(accA[2]);
    float h0A = sigf(accA[3]) * tanhfast(c0A);
    c0B = sigf(accB[1]) * c0B + sigf(accB[0]) * tanhfast(accB[2]);
    float h0B = sigf(accB[3]) * tanhfast(c0B);
    unsigned vA0 = f2h(h0A), vB0 = f2h(h0B);
    unsigned vA1 = __shfl_down(vA0, 16, 64);
    unsigned vB1 = __shfl_down(vB0, 16, 64);
    if ((ul & 1) == 0) {
      u64 wA = 1ULL | ((u64)vA0 << 16) | ((u64)vA1 << 32);
      u64 wB = 1ULL | ((u64)vB0 << 16) | ((u64)vB1 << 32);
      __hip_atomic_store(st0A, wA, __ATOMIC_RELAXED, __HIP_MEMORY_SCOPE_AGENT);
      __hip_atomic_store(st0B, wB, __ATOMIC_RELAXED, __HIP_MEMORY_SCOPE_AGENT);
    }
  }

  // --- main loop: one iteration = one timestep for BOTH chains ---
  for (int t = 0; t < 256; t++) {
    // prefetch x(t+1) both chains
    short8 xaA[4], xaB[4];
    if (t < 255) {
      const unsigned short* xpA = seq + ((b0A + bt) * 256 + (t + 1)) * 128 + q8;
      const unsigned short* xpB = seq + ((b0B + bt) * 256 + (t + 1)) * 128 + q8;
#pragma unroll
      for (int m = 0; m < 4; m++) {
        xaA[m] = *(const short8*)(xpA + m * 32);
        xaB[m] = *(const short8*)(xpB + m * 32);
      }
    }
    const u64* q0A = h0w + (t & 1) * 32768 + gA * 2048;
    const u64* q0B = h0w + (t & 1) * 32768 + gB * 2048;
    const unsigned e0 = (unsigned)(unsigned short)(t + 1);
    const unsigned e1 = (unsigned)(unsigned short)t;
    // ---- combined h0 poll, both chains (r7-style full reload) ----
    u64 w0A[8], w0B[8];
    for (;;) {
      bool ok = true;
#pragma unroll
      for (int u = 0; u < 8; u++) {
        w0A[u] = __hip_atomic_load(q0A + u * 256 + tid, __ATOMIC_RELAXED,
                                   __HIP_MEMORY_SCOPE_AGENT);
        w0B[u] = __hip_atomic_load(q0B + u * 256 + tid, __ATOMIC_RELAXED,
                                   __HIP_MEMORY_SCOPE_AGENT);
      }
#pragma unroll
      for (int u = 0; u < 8; u++)
        ok = ok & ((unsigned)(unsigned short)w0A[u] == e0) &
             ((unsigned)(unsigned short)w0B[u] == e0);
      if (__all(ok)) break;
    }
    // ---- unpack both to LDS; single barrier per iteration ----
    const int hb = t & 1;
#pragma unroll
    for (int u = 0; u < 8; u++) {
      int g = u * 256 + tid;
      int bw = g & 15, p = g >> 4;
      *(unsigned*)&hsA[hb][bw * 264 + 2 * p] = (unsigned)(w0A[u] >> 16);
      *(unsigned*)&hsB[hb][bw * 264 + 2 * p] = (unsigned)(w0B[u] >> 16);
    }
    __syncthreads();
    short8 haA[8], haB[8];
#pragma unroll
    for (int kk = 0; kk < 8; kk++) {
      haA[kk] = *(const short8*)&hsA[hb][bt * 264 + kk * 32 + q8];
      haB[kk] = *(const short8*)&hsB[hb][bt * 264 + kk * 32 + q8];
    }
    // ---- layer0 both chains, shared weight reads; store h0 EARLY ----
    if (t < 255) {
      f32x4 aA = b0v, bA = {0.f, 0.f, 0.f, 0.f};
      f32x4 aB = b0v, bB = {0.f, 0.f, 0.f, 0.f};
      {
        short8 lw;
        lw = LW(0); aA = MFMA(lw, xaA[0], aA); aB = MFMA(lw, xaB[0], aB);
        lw = LW(1); bA = MFMA(lw, xaA[1], bA); bB = MFMA(lw, xaB[1], bB);
        lw = LW(2); aA = MFMA(lw, xaA[2], aA); aB = MFMA(lw, xaB[2], aB);
        lw = LW(3); bA = MFMA(lw, xaA[3], bA); bB = MFMA(lw, xaB[3], bB);
#pragma unroll
        for (int kk = 0; kk < 8; kk += 2) {
          lw = LW(4 + kk);
          aA = MFMA(lw, haA[kk], aA); aB = MFMA(lw, haB[kk], aB);
          lw = LW(5 + kk);
          bA = MFMA(lw, haA[kk + 1], bA); bB = MFMA(lw, haB[kk + 1], bB);
        }
      }
      float giA = aA[0] + bA[0], gfA = aA[1] + bA[1];
      float ggA = aA[2] + bA[2], goA = aA[3] + bA[3];
      c0A = sigf(gfA) * c0A + sigf(giA) * tanhfast(ggA);
      float h0A = sigf(goA) * tanhfast(c0A);
      float giB = aB[0] + bB[0], gfB = aB[1] + bB[1];
      float ggB = aB[2] + bB[2], goB = aB[3] + bB[3];
      c0B = sigf(gfB) * c0B + sigf(giB) * tanhfast(ggB);
      float h0B = sigf(goB) * tanhfast(c0B);
      unsigned vA0 = f2h(h0A), vB0 = f2h(h0B);
      unsigned vA1 = __shfl_down(vA0, 16, 64);
      unsigned vB1 = __shfl_down(vB0, 16, 64);
      if ((ul & 1) == 0) {
        u64 tg = (u64)(unsigned short)(t + 2);
        u64 wA = tg | ((u64)vA0 << 16) | ((u64)vA1 << 32);
        u64 wB = tg | ((u64)vB0 << 16) | ((u64)vB1 << 32);
        __hip_atomic_store(st0A + ((t + 1) & 1) * 32768, wA, __ATOMIC_RELAXED,
                           __HIP_MEMORY_SCOPE_AGENT);
        __hip_atomic_store(st0B + ((t + 1) & 1) * 32768, wB, __ATOMIC_RELAXED,
                           __HIP_MEMORY_SCOPE_AGENT);
      }
    }
    // ---- layer1 part A (h0 operand), both chains, shared weights ----
    f32x4 acc1A = b1v, acc1B = b1v;
#pragma unroll
    for (int kk = 0; kk < 8; kk++) {
      short8 lw = LW(12 + kk);
      acc1A = MFMA(lw, haA[kk], acc1A);
      acc1B = MFMA(lw, haB[kk], acc1B);
    }
    // ---- chain A: h1(t-1) direct fragment loads + layer1 part B ----
    {
      const u64* fpA = h1w + ((t + 2) % 3) * 32768 + gA * 2048 + fw0;
      u64 wd[32];
      for (;;) {
        bool ok = true;
#pragma unroll
        for (int kk = 0; kk < 8; kk++)
#pragma unroll
          for (int j = 0; j < 4; j++)
            wd[kk * 4 + j] = __hip_atomic_load(fpA + kk * 256 + j * 16,
                                               __ATOMIC_RELAXED,
                                               __HIP_MEMORY_SCOPE_AGENT);
#pragma unroll
        for (int m = 0; m < 32; m++)
          ok = ok & ((unsigned)(unsigned short)wd[m] == e1);
        if (__all(ok)) break;
      }
      f32x4 acc1b = {0.f, 0.f, 0.f, 0.f};
#pragma unroll
      for (int kk = 0; kk < 8; kk++) {
        union { unsigned u[4]; short8 s8; } cv;
#pragma unroll
        for (int j = 0; j < 4; j++) cv.u[j] = (unsigned)(wd[kk * 4 + j] >> 16);
        acc1b = MFMA(LW(20 + kk), cv.s8, acc1b);
      }
      float gi = acc1A[0] + acc1b[0], gf = acc1A[1] + acc1b[1];
      float gg = acc1A[2] + acc1b[2], go = acc1A[3] + acc1b[3];
      c1A = sigf(gf) * c1A + sigf(gi) * tanhfast(gg);
      h1vA = sigf(go) * tanhfast(c1A);
      if (t < 255) {
        unsigned v0 = f2h(h1vA);
        unsigned v1 = __shfl_down(v0, 16, 64);
        if ((ul & 1) == 0) {
          u64 w = (u64)(unsigned short)(t + 1) | ((u64)v0 << 16) | ((u64)v1 << 32);
          __hip_atomic_store(st1A + (t % 3) * 32768, w, __ATOMIC_RELAXED,
                             __HIP_MEMORY_SCOPE_AGENT);
        }
      }
    }
    // ---- chain B: same ----
    {
      const u64* fpB = h1w + ((t + 2) % 3) * 32768 + gB * 2048 + fw0;
      u64 wd[32];
      for (;;) {
        bool ok = true;
#pragma unroll
        for (int kk = 0; kk < 8; kk++)
#pragma unroll
          for (int j = 0; j < 4; j++)
            wd[kk * 4 + j] = __hip_atomic_load(fpB + kk * 256 + j * 16,
                                               __ATOMIC_RELAXED,
                                               __HIP_MEMORY_SCOPE_AGENT);
#pragma unroll
        for (int m = 0; m < 32; m++)
          ok = ok & ((unsigned)(unsigned short)wd[m] == e1);
        if (__all(ok)) break;
      }
      f32x4 acc1b = {0.f, 0.f, 0.f, 0.f};
#pragma unroll
      for (int kk = 0; kk < 8; kk++) {
        union { unsigned u[4]; short8 s8; } cv;
#pragma unroll
        for (int j = 0; j < 4; j++) cv.u[j] = (unsigned)(wd[kk * 4 + j] >> 16);
        acc1b = MFMA(LW(20 + kk), cv.s8, acc1b);
      }
      float gi = acc1B[0] + acc1b[0], gf = acc1B[1] + acc1b[1];
      float gg = acc1B[2] + acc1b[2], go = acc1B[3] + acc1b[3];
      c1B = sigf(gf) * c1B + sigf(gi) * tanhfast(gg);
      h1vB = sigf(go) * tanhfast(c1B);
      if (t < 255) {
        unsigned v0 = f2h(h1vB);
        unsigned v1 = __shfl_down(v0, 16, 64);
        if ((ul & 1) == 0) {
          u64 w = (u64)(unsigned short)(t + 1) | ((u64)v0 << 16) | ((u64)v1 << 32);
          __hip_atomic_store(st1B + (t % 3) * 32768, w, __ATOMIC_RELAXED,
                             __HIP_MEMORY_SCOPE_AGENT);
        }
      }
    }
  }
  hfinal[(b0A + bt) * 256 + sh * 16 + wv * 4 + ul] = h1vA;
  hfinal[(b0B + bt) * 256 + sh * 16 + wv * 4 + ul] = h1vB;
}

// ---------------- MLP head ----------------
__global__ __launch_bounds__(256, 2) void k_mlp(const float* __restrict__ hfinal,
                                                const float* __restrict__ s,
                                                const float* __restrict__ w1,
                                                const float* __restrict__ b1,
                                                const float* __restrict__ w2,
                                                const float* __restrict__ b2,
                                                const float* __restrict__ wp,
                                                const float* __restrict__ bp,
                                                float* __restrict__ out) {
  __shared__ float feat[257];
  __shared__ float z1[256];
  __shared__ float z2[128];
  const int tid = threadIdx.x, b = blockIdx.x;
  feat[tid] = hfinal[b * 256 + tid];
  if (tid == 0) feat[256] = s[b];
  __syncthreads();
  float a = b1[tid];
  for (int i = 0; i < 257; i++) a += feat[i] * w1[i * 256 + tid];
  z1[tid] = fmaxf(a, 0.f);
  __syncthreads();
  if (tid < 128) {
    float a2 = b2[tid];
    for (int i = 0; i < 256; i++) a2 += z1[i] * w2[i * 128 + tid];
    z2[tid] = fmaxf(a2, 0.f);
  }
  __syncthreads();
  if (tid == 0) {
    float sv = bp[0];
    for (int i = 0; i < 128; i++) sv += z2[i] * wp[i];
    out[b] = fmaxf(sv, 0.f) + log1pf(__expf(-fabsf(sv)));
  }
}

extern "C" void kernel_launch(void* const* d_in, const int* in_sizes, int n_in,
                              void* d_out, int out_size, void* d_ws, size_t ws_size,
                              hipStream_t stream) {
  const float* x = (const float*)d_in[0];
  const float* s = (const float*)d_in[1];
  const float* c1w = (const float*)d_in[2];
  const float* c1b = (const float*)d_in[3];
  const float* bn1g = (const float*)d_in[4];
  const float* bn1b = (const float*)d_in[5];
  const float* c2w = (const float*)d_in[6];
  const float* c2b = (const float*)d_in[7];
  const float* bn2g = (const float*)d_in[8];
  const float* bn2b = (const float*)d_in[9];
  const float* wi0 = (const float*)d_in[10];
  const float* bi0 = (const float*)d_in[11];
  const float* wh0 = (const float*)d_in[12];
  const float* bh0 = (const float*)d_in[13];
  const float* wi1 = (const float*)d_in[14];
  const float* bi1 = (const float*)d_in[15];
  const float* wh1 = (const float*)d_in[16];
  const float* bh1 = (const float*)d_in[17];
  const float* w1 = (const float*)d_in[18];
  const float* b1 = (const float*)d_in[19];
  const float* w2 = (const float*)d_in[20];
  const float* b2 = (const float*)d_in[21];
  const float* wp = (const float*)d_in[22];
  const float* bp = (const float*)d_in[23];

  char* ws = (char*)d_ws;
  float* sc1 = (float*)(ws + OFF_SC1);
  float* sh1 = (float*)(ws + OFF_SH1);
  float* sc2 = (float*)(ws + OFF_SC2);
  float* sh2 = (float*)(ws + OFF_SH2);
  float* b0arr = (float*)(ws + OFF_B0);
  float* b1arr = (float*)(ws + OFF_B1);
  float* part1 = (float*)(ws + OFF_PART1);
  float* part2 = (float*)(ws + OFF_PART2);
  unsigned short* w2f = (unsigned short*)(ws + OFF_W2F);
  unsigned short* wf = (unsigned short*)(ws + OFF_WF);
  unsigned short* seq = (unsigned short*)(ws + OFF_SEQ);
  u64* h0w = (u64*)(ws + OFF_H0W);
  u64* h1w = (u64*)(ws + OFF_H1W);
  float* hf = (float*)(ws + OFF_HF);

  k_init<<<640, 256, 0, stream>>>(h0w);  // zeros h0w (512KB) + h1w (768KB)
  k_conv1<<<256, 256, 0, stream>>>(x, c1w, c1b, part1);
  k_bn1<<<64, 256, 0, stream>>>(part1, bn1g, bn1b, sc1, sh1);
  k_w2frag<<<160, 256, 0, stream>>>(c2w, w2f);
  k_conv2<<<256, 256, 0, stream>>>(x, c1w, c1b, sc1, sh1, w2f, c2b, seq, part2);
  k_bn2<<<128, 256, 0, stream>>>(part2, bn2g, bn2b, sc2, sh2);
  k_bias<<<4, 256, 0, stream>>>(bi0, bh0, wi0, sh2, bi1, bh1, b0arr, b1arr);
  k_wfrag<<<3584, 256, 0, stream>>>(wi0, wh0, wi1, wh1, sc2, wf);
  k_lstm<<<128, 256, 0, stream>>>(seq, wf, b0arr, b1arr, h0w, h1w, hf);
  k_mlp<<<256, 256, 0, stream>>>(hf, s, w1, b1, w2, b2, wp, bp, (float*)d_out);
}

// Round 14
// 972.624 us; speedup vs baseline: 1.4622x; 1.4622x over previous
//
#include <hip/hip_runtime.h>
#include <hip/hip_bf16.h>
#include <hip/hip_fp16.h>
#include <math.h>

#define EPSV 1e-5f

typedef short short8 __attribute__((ext_vector_type(8)));
typedef float f32x4 __attribute__((ext_vector_type(4)));
typedef unsigned long long u64;

#define MFMA(a, b, c) __builtin_amdgcn_mfma_f32_16x16x32_f16(a, b, c, 0, 0, 0)

// ---------------- ws layout (bytes) ----------------
#define OFF_SC1    8192            // 64 f32
#define OFF_SH1    8448
#define OFF_SC2    8704            // 128 f32
#define OFF_SH2    9216
#define OFF_B0     9728            // 1024 f32 = 4096
#define OFF_B1     13824           // 4096
#define OFF_PART1  17920           // 256*64*2*4 = 131072
#define OFF_PART2  148992          // 256*128*2*4 = 262144
#define OFF_W2F    411136          // 40960 f16 = 81920
#define OFF_WF     493056          // 917504 f16 = 1835008
#define OFF_SEQ    2328064         // 256*256*128*2 = 16777216 (f16 [b][t][c])
#define OFF_H0W    19105280        // 2*16*128*16*8 = 524288 (tagged u64, depth-2)
#define OFF_H1W    19629568        // 3*16*128*16*8 = 786432 (depth-3)
#define OFF_HF     20416000        // 256*256*4 = 262144 (f32)
// end 20,678,144

__device__ __forceinline__ unsigned short f2h(float f) {
  return __half_as_ushort(__float2half(f));
}
__device__ __forceinline__ float h2f(unsigned short u) {
  return __half2float(__ushort_as_half(u));
}
__device__ __forceinline__ float sigf(float x) { return 1.f / (1.f + __expf(-x)); }
__device__ __forceinline__ float tanhfast(float x) {
  return 1.f - 2.f / (__expf(2.f * x) + 1.f);
}

// ---------------- init: zero tagged h word buffers (1.25 MB) ----------------
__global__ void k_init(u64* hz) {
  int i = blockIdx.x * 256 + threadIdx.x;  // grid 640 -> 163840 u64
  if (i < 163840) hz[i] = 0ULL;
}

// ---------------- conv1 + relu + pool4, BN1 partial stats ----------------
__global__ __launch_bounds__(256, 2) void k_conv1(const float* __restrict__ x,
                                                  const float* __restrict__ w1,
                                                  const float* __restrict__ b1,
                                                  float* __restrict__ part1) {
  __shared__ float xs[4104];
  __shared__ float w1s[576];
  __shared__ float b1s[64];
  __shared__ float red[64][4][2];
  const int tid = threadIdx.x, b = blockIdx.x;
  for (int j = tid; j < 4104; j += 256) {
    int p = j - 4;
    xs[j] = (p >= 0 && p < 4096) ? x[b * 4096 + p] : 0.f;
  }
  for (int j = tid; j < 576; j += 256) w1s[j] = w1[j];
  if (tid < 64) b1s[tid] = b1[tid];
  __syncthreads();
  const int c = tid >> 2, lq = tid & 3;
  float wr[9];
#pragma unroll
  for (int k = 0; k < 9; k++) wr[k] = w1s[c * 9 + k];
  const float bb = b1s[c];
  float S = 0.f, SS = 0.f;
  for (int li = 0; li < 256; li++) {
    int l = lq * 256 + li;
    int base = 4 * l;
    float a4 = 0.f;
#pragma unroll
    for (int jj = 0; jj < 4; jj++) {
      float cv = bb;
#pragma unroll
      for (int k = 0; k < 9; k++) cv += xs[base + jj + k] * wr[k];
      a4 += fmaxf(cv, 0.f);
    }
    float y = 0.25f * a4;
    S += y;
    SS += y * y;
  }
  red[c][lq][0] = S;
  red[c][lq][1] = SS;
  __syncthreads();
  if (tid < 64) {
    float s = 0.f, ss = 0.f;
#pragma unroll
    for (int q = 0; q < 4; q++) {
      s += red[tid][q][0];
      ss += red[tid][q][1];
    }
    part1[(b * 64 + tid) * 2 + 0] = s;
    part1[(b * 64 + tid) * 2 + 1] = ss;
  }
}

// ---------------- BN1 finalize ----------------
__global__ void k_bn1(const float* __restrict__ part1, const float* __restrict__ g,
                      const float* __restrict__ bt, float* __restrict__ sc,
                      float* __restrict__ sh) {
  __shared__ float rs[256], rss[256];
  const int c = blockIdx.x, tid = threadIdx.x;
  rs[tid] = part1[(tid * 64 + c) * 2 + 0];
  rss[tid] = part1[(tid * 64 + c) * 2 + 1];
  __syncthreads();
  for (int st = 128; st > 0; st >>= 1) {
    if (tid < st) {
      rs[tid] += rs[tid + st];
      rss[tid] += rss[tid + st];
    }
    __syncthreads();
  }
  if (tid == 0) {
    const float N = 256.f * 1024.f;
    float mean = rs[0] / N;
    float var = rss[0] / N - mean * mean;
    float scale = g[c] * rsqrtf(var + EPSV);
    sc[c] = scale;
    sh[c] = bt[c] - mean * scale;
  }
}

// ---------------- w2 -> MFMA B-fragment layout (f16) ----------------
__global__ void k_w2frag(const float* __restrict__ w2,
                         unsigned short* __restrict__ w2f) {
  int n = blockIdx.x * 256 + threadIdx.x;  // < 40960
  if (n >= 40960) return;
  int e = n & 7, lane = (n >> 3) & 63, ot = (n >> 9) & 7, sc = n >> 12;
  int s = sc >> 1, c2 = sc & 1;
  int o = ot * 16 + (lane & 15);
  int i = c2 * 32 + ((lane >> 4) << 3) + e;
  w2f[n] = f2h(w2[o * 320 + i * 5 + s]);
}

// ---------------- conv2 via MFMA (recomputes conv1+bn1 into LDS y1t) -------
__global__ __launch_bounds__(256, 1) void k_conv2(
    const float* __restrict__ x, const float* __restrict__ w1,
    const float* __restrict__ b1, const float* __restrict__ sc1,
    const float* __restrict__ sh1, const unsigned short* __restrict__ w2f,
    const float* __restrict__ b2, unsigned short* __restrict__ seq,
    float* __restrict__ part2) {
  __shared__ float xs[4104];
  __shared__ unsigned short y1t[1028][66];  // row = l+2, col = i
  __shared__ float w1s[576], b1s[64], s1s[64], h1s[64], b2s[128];
  __shared__ float red[4][2][128];
  const int tid = threadIdx.x, b = blockIdx.x;
  for (int j = tid; j < 4104; j += 256) {
    int p = j - 4;
    xs[j] = (p >= 0 && p < 4096) ? x[b * 4096 + p] : 0.f;
  }
  for (int j = tid; j < 576; j += 256) w1s[j] = w1[j];
  if (tid < 64) {
    b1s[tid] = b1[tid];
    s1s[tid] = sc1[tid];
    h1s[tid] = sh1[tid];
  }
  if (tid < 128) b2s[tid] = b2[tid];
  if (tid < 132) {
    int r4 = tid / 33, c4 = tid % 33;
    int row = (r4 < 2) ? r4 : (1024 + r4);
    ((unsigned int*)&y1t[row][0])[c4] = 0u;
  }
  __syncthreads();
  {
    const int i2 = tid & 31, lg = tid >> 5;
    const int ia = 2 * i2, ib = ia + 1;
    float wra[9], wrb[9];
#pragma unroll
    for (int k = 0; k < 9; k++) {
      wra[k] = w1s[ia * 9 + k];
      wrb[k] = w1s[ib * 9 + k];
    }
    const float bia = b1s[ia], bib = b1s[ib];
    const float sa = s1s[ia], sb = s1s[ib], ha = h1s[ia], hb = h1s[ib];
    for (int j = 0; j < 128; j++) {
      int l = lg * 128 + j;
      float xv[12];
#pragma unroll
      for (int m = 0; m < 12; m++) xv[m] = xs[4 * l + m];
      float aa = 0.f, ab = 0.f;
#pragma unroll
      for (int jj = 0; jj < 4; jj++) {
        float ca = bia, cb = bib;
#pragma unroll
        for (int k = 0; k < 9; k++) {
          float xx = xv[jj + k];
          ca += xx * wra[k];
          cb += xx * wrb[k];
        }
        aa += fmaxf(ca, 0.f);
        ab += fmaxf(cb, 0.f);
      }
      float va = 0.25f * aa * sa + ha;
      float vb = 0.25f * ab * sb + hb;
      unsigned int pk = (unsigned int)f2h(va) | ((unsigned int)f2h(vb) << 16);
      *(unsigned int*)&y1t[l + 2][ia] = pk;
    }
  }
  __syncthreads();
  const int wv = tid >> 6, lane = tid & 63;
  const int colo = lane & 15, rq = lane >> 4;
  float Sa[2][4], SSa[2][4];
#pragma unroll
  for (int a = 0; a < 2; a++)
#pragma unroll
    for (int c = 0; c < 4; c++) {
      Sa[a][c] = 0.f;
      SSa[a][c] = 0.f;
    }
#pragma unroll
  for (int og = 0; og < 2; og++) {
    short8 bf[4][10];
#pragma unroll
    for (int ot = 0; ot < 4; ot++)
#pragma unroll
      for (int sc = 0; sc < 10; sc++)
        bf[ot][sc] = *(const short8*)(w2f + ((sc * 8 + og * 4 + ot) * 64 + lane) * 8);
    for (int ltw = 0; ltw < 16; ltw++) {
      int lt = wv * 16 + ltw;
      int lbase = lt * 16;
      short8 af[10];
#pragma unroll
      for (int s = 0; s < 5; s++)
#pragma unroll
        for (int c2 = 0; c2 < 2; c2++)
          af[s * 2 + c2] =
              *(const short8*)&y1t[lbase + colo + s][c2 * 32 + rq * 8];
#pragma unroll
      for (int ot = 0; ot < 4; ot++) {
        f32x4 acc = {0.f, 0.f, 0.f, 0.f};
#pragma unroll
        for (int sc = 0; sc < 10; sc++)
          acc = MFMA(af[sc], bf[ot][sc], acc);
        int o = (og * 4 + ot) * 16 + colo;
        float bv = b2s[o];
        float s4 = fmaxf(acc[0] + bv, 0.f) + fmaxf(acc[1] + bv, 0.f) +
                   fmaxf(acc[2] + bv, 0.f) + fmaxf(acc[3] + bv, 0.f);
        float y = 0.25f * s4;
        int t_out = lt * 4 + rq;
        seq[(b * 256 + t_out) * 128 + o] = f2h(y);
        Sa[og][ot] += y;
        SSa[og][ot] += y * y;
      }
    }
  }
#pragma unroll
  for (int og = 0; og < 2; og++)
#pragma unroll
    for (int ot = 0; ot < 4; ot++) {
      float sv = Sa[og][ot], ssv = SSa[og][ot];
      sv += __shfl_xor(sv, 16, 64);
      sv += __shfl_xor(sv, 32, 64);
      ssv += __shfl_xor(ssv, 16, 64);
      ssv += __shfl_xor(ssv, 32, 64);
      if (rq == 0) {
        int o = (og * 4 + ot) * 16 + colo;
        red[wv][0][o] = sv;
        red[wv][1][o] = ssv;
      }
    }
  __syncthreads();
  if (tid < 128) {
    float s = red[0][0][tid] + red[1][0][tid] + red[2][0][tid] + red[3][0][tid];
    float ss = red[0][1][tid] + red[1][1][tid] + red[2][1][tid] + red[3][1][tid];
    part2[(b * 128 + tid) * 2 + 0] = s;
    part2[(b * 128 + tid) * 2 + 1] = ss;
  }
}

// ---------------- BN2 finalize ----------------
__global__ void k_bn2(const float* __restrict__ part2, const float* __restrict__ g,
                      const float* __restrict__ bt, float* __restrict__ sc,
                      float* __restrict__ sh) {
  __shared__ float rs[256], rss[256];
  const int o = blockIdx.x, tid = threadIdx.x;
  rs[tid] = part2[(tid * 128 + o) * 2 + 0];
  rss[tid] = part2[(tid * 128 + o) * 2 + 1];
  __syncthreads();
  for (int st = 128; st > 0; st >>= 1) {
    if (tid < st) {
      rs[tid] += rs[tid + st];
      rss[tid] += rss[tid + st];
    }
    __syncthreads();
  }
  if (tid == 0) {
    const float N = 65536.f;
    float mean = rs[0] / N;
    float var = rss[0] / N - mean * mean;
    float scale = g[o] * rsqrtf(var + EPSV);
    sc[o] = scale;
    sh[o] = bt[o] - mean * scale;
  }
}

// ---------------- fold BN2 shift into layer-0 bias ----------------
__global__ void k_bias(const float* __restrict__ bi0, const float* __restrict__ bh0,
                       const float* __restrict__ wi0, const float* __restrict__ sh2,
                       const float* __restrict__ bi1, const float* __restrict__ bh1,
                       float* __restrict__ b0arr, float* __restrict__ b1arr) {
  int g = blockIdx.x * 256 + threadIdx.x;  // < 1024
  float s = bi0[g] + bh0[g];
  for (int k = 0; k < 128; k++) s += sh2[k] * wi0[k * 1024 + g];
  b0arr[g] = s;
  b1arr[g] = bi1[g] + bh1[g];
}

// ---------------- LSTM weights -> A-fragment layout (f16, BN2-scaled) -------
__global__ void k_wfrag(const float* __restrict__ wi0, const float* __restrict__ wh0,
                        const float* __restrict__ wi1, const float* __restrict__ wh1,
                        const float* __restrict__ sc2,
                        unsigned short* __restrict__ wf) {
  const int slot = blockIdx.x / 56;
  const int idx = (blockIdx.x % 56) * 256 + threadIdx.x;  // < 14336
  const int j = idx >> 9, lane = (idx >> 3) & 63, e = idx & 7;
  const int sh = slot >> 2, wv = slot & 3;
  const int m = lane & 15;
  const int gcol = (m & 3) * 256 + sh * 16 + wv * 4 + (m >> 2);
  float v;
  if (j < 12) {
    int k = j * 32 + ((lane >> 4) << 3) + e;
    v = (k < 128) ? sc2[k] * wi0[k * 1024 + gcol] : wh0[(k - 128) * 1024 + gcol];
  } else {
    int k = (j - 12) * 32 + ((lane >> 4) << 3) + e;
    v = (k < 256) ? wi1[k * 1024 + gcol] : wh1[(k - 256) * 1024 + gcol];
  }
  wf[slot * 14336 + idx] = f2h(v);
}

// ---------------- persistent 2-layer LSTM, wave-autonomous, barrier-free ---
// grid 256: gb = blockIdx&15 (same-XCD group), sh = blockIdx>>4.
// Each wave is a fully independent 16-unit recurrence engine: sentinel poll,
// direct per-thread fragment loads (words carry tag+data), no in-loop LDS/
// barriers. h0 depth-2, h1 depth-3 (r12-proven). Wave coverage: the 64 lanes'
// fragment words tile the entire group panel, so __all-validation implies the
// wave observed every producer's tag before it stores (safety as r7/r12).
// word = [tag:16 | h(2p):16 | h(2p+1):16 | 0:16], layout [buf][g][pair][batch]
__global__ __launch_bounds__(256, 1) void k_lstm(
    const unsigned short* __restrict__ seq, const unsigned short* __restrict__ wf,
    const float* __restrict__ b0arr, const float* __restrict__ b1arr,
    u64* __restrict__ h0w, u64* __restrict__ h1w, float* __restrict__ hfinal) {
  __shared__ unsigned short wlds[4 * 28 * 64 * 8];  // 114688 B
  const int tid = threadIdx.x;
  const int gb = blockIdx.x & 15, sh = blockIdx.x >> 4;
  const int b0 = gb * 16;
  const int wv = tid >> 6, lane = tid & 63;
  const int bt = lane & 15;   // batch-local (B-frag col / D col)
  const int ul = lane >> 4;   // unit-local (D row quad / B-frag k-quad)
  const int q8 = ul * 8;

  // ---- stage weight A-fragments into LDS (one copy, fragment-ordered) ----
  {
    const u64* src = (const u64*)(wf + sh * 4 * 14336);
    u64* dst = (u64*)wlds;
    for (int j = tid; j < 14336; j += 256) dst[j] = src[j];
  }
#define LW(j) (*(const short8*)&wlds[(((wv)*28 + (j)) * 64 + lane) * 8])

  f32x4 b0v, b1v;
#pragma unroll
  for (int r = 0; r < 4; r++) {
    int gcol = r * 256 + sh * 16 + wv * 4 + ul;
    b0v[r] = b0arr[gcol];
    b1v[r] = b1arr[gcol];
  }
  float c0 = 0.f, c1 = 0.f, h1v = 0.f;
  const int pidx = (sh * 8 + wv * 2 + (ul >> 1)) * 16 + bt;  // store slot
  u64* const st0base = h0w + gb * 2048 + pidx;
  u64* const st1base = h1w + gb * 2048 + pidx;
  const int fw0 = ul * 64 + bt;  // fragment-word base: + kk*256 + j*16
  __syncthreads();  // weights staged (sole block barrier, prologue only)

  // --- prologue: h0(0) = cell(x(0), c=0); tag 1 into h0w buf0 ---
  {
    const unsigned short* xp = seq + ((b0 + bt) * 256 + 0) * 128 + q8;
    short8 xa0 = *(const short8*)(xp + 0);
    short8 xa1 = *(const short8*)(xp + 32);
    short8 xa2 = *(const short8*)(xp + 64);
    short8 xa3 = *(const short8*)(xp + 96);
    f32x4 acc = b0v;
    acc = MFMA(LW(0), xa0, acc);
    acc = MFMA(LW(1), xa1, acc);
    acc = MFMA(LW(2), xa2, acc);
    acc = MFMA(LW(3), xa3, acc);
    c0 = sigf(acc[1]) * c0 + sigf(acc[0]) * tanhfast(acc[2]);
    float h0v = sigf(acc[3]) * tanhfast(c0);
    unsigned v0 = f2h(h0v);
    unsigned v1 = __shfl_down(v0, 16, 64);
    if ((ul & 1) == 0) {
      u64 w = 1ULL | ((u64)v0 << 16) | ((u64)v1 << 32);
      __hip_atomic_store(st0base, w, __ATOMIC_RELAXED, __HIP_MEMORY_SCOPE_AGENT);
    }
  }

  // --- main loop (no barriers) ---
  for (int t = 0; t < 256; t++) {
    short8 xa0, xa1, xa2, xa3;
    if (t < 255) {
      const unsigned short* xp = seq + ((b0 + bt) * 256 + (t + 1)) * 128 + q8;
      xa0 = *(const short8*)(xp + 0);
      xa1 = *(const short8*)(xp + 32);
      xa2 = *(const short8*)(xp + 64);
      xa3 = *(const short8*)(xp + 96);
    }
    const u64* q0 = h0w + (t & 1) * 32768 + gb * 2048;
    const u64* q1 = h1w + ((t + 2) % 3) * 32768 + gb * 2048;
    const unsigned e0 = (unsigned)(unsigned short)(t + 1);
    const unsigned e1 = (unsigned)(unsigned short)t;
    // ---- sentinel prefilter (h0 only; h1 is a step old) ----
    {
      const u64* s0p = q0 + tid * 8;
      for (;;) {
        u64 s0 = __hip_atomic_load(s0p, __ATOMIC_RELAXED, __HIP_MEMORY_SCOPE_AGENT);
        if (__all((unsigned)(unsigned short)s0 == e0)) break;
      }
    }
    // ---- h0 direct fragment pass (validate, rare retry) ----
    short8 ha[8];
    {
      const u64* fp = q0 + fw0;
      for (;;) {
        bool ok = true;
#pragma unroll
        for (int kk = 0; kk < 8; kk++) {
          union { unsigned u[4]; short8 s8; } cv;
#pragma unroll
          for (int j = 0; j < 4; j++) {
            u64 w = __hip_atomic_load(fp + kk * 256 + j * 16, __ATOMIC_RELAXED,
                                      __HIP_MEMORY_SCOPE_AGENT);
            ok = ok & ((unsigned)(unsigned short)w == e0);
            cv.u[j] = (unsigned)(w >> 16);
          }
          ha[kk] = cv.s8;
        }
        if (__all(ok)) break;
      }
    }
    // ---- layer0: 12 MFMA, cell0, EARLY h0 store ----
    if (t < 255) {
      f32x4 a0a = b0v;
      f32x4 a0b = {0.f, 0.f, 0.f, 0.f};
      a0a = MFMA(LW(0), xa0, a0a);
      a0b = MFMA(LW(1), xa1, a0b);
      a0a = MFMA(LW(2), xa2, a0a);
      a0b = MFMA(LW(3), xa3, a0b);
#pragma unroll
      for (int kk = 0; kk < 8; kk += 2) {
        a0a = MFMA(LW(4 + kk), ha[kk], a0a);
        a0b = MFMA(LW(5 + kk), ha[kk + 1], a0b);
      }
      float gi = a0a[0] + a0b[0], gf = a0a[1] + a0b[1];
      float gg = a0a[2] + a0b[2], go = a0a[3] + a0b[3];
      c0 = sigf(gf) * c0 + sigf(gi) * tanhfast(gg);
      float h0v = sigf(go) * tanhfast(c0);
      unsigned v0 = f2h(h0v);
      unsigned v1 = __shfl_down(v0, 16, 64);
      if ((ul & 1) == 0) {
        u64 w = (u64)(unsigned short)(t + 2) | ((u64)v0 << 16) | ((u64)v1 << 32);
        __hip_atomic_store(st0base + ((t + 1) & 1) * 32768, w, __ATOMIC_RELAXED,
                           __HIP_MEMORY_SCOPE_AGENT);
      }
    }
    // ---- layer1 part A (h0 operand) ----
    f32x4 acc1a = b1v;
#pragma unroll
    for (int kk = 0; kk < 8; kk++) acc1a = MFMA(LW(12 + kk), ha[kk], acc1a);
    // ---- h1(t-1) direct fragment pass (one step old; passes first try) ----
    f32x4 acc1b = {0.f, 0.f, 0.f, 0.f};
    {
      const u64* fp = q1 + fw0;
      short8 hbf[8];
      for (;;) {
        bool ok = true;
#pragma unroll
        for (int kk = 0; kk < 8; kk++) {
          union { unsigned u[4]; short8 s8; } cv;
#pragma unroll
          for (int j = 0; j < 4; j++) {
            u64 w = __hip_atomic_load(fp + kk * 256 + j * 16, __ATOMIC_RELAXED,
                                      __HIP_MEMORY_SCOPE_AGENT);
            ok = ok & ((unsigned)(unsigned short)w == e1);
            cv.u[j] = (unsigned)(w >> 16);
          }
          hbf[kk] = cv.s8;
        }
        if (__all(ok)) break;
      }
#pragma unroll
      for (int kk = 0; kk < 8; kk++) acc1b = MFMA(LW(20 + kk), hbf[kk], acc1b);
    }
    // ---- cell1 + h1 store ----
    {
      float gi = acc1a[0] + acc1b[0], gf = acc1a[1] + acc1b[1];
      float gg = acc1a[2] + acc1b[2], go = acc1a[3] + acc1b[3];
      c1 = sigf(gf) * c1 + sigf(gi) * tanhfast(gg);
      h1v = sigf(go) * tanhfast(c1);
      if (t < 255) {
        unsigned v0 = f2h(h1v);
        unsigned v1 = __shfl_down(v0, 16, 64);
        if ((ul & 1) == 0) {
          u64 w = (u64)(unsigned short)(t + 1) | ((u64)v0 << 16) | ((u64)v1 << 32);
          __hip_atomic_store(st1base + (t % 3) * 32768, w, __ATOMIC_RELAXED,
                             __HIP_MEMORY_SCOPE_AGENT);
        }
      }
    }
  }
  hfinal[(b0 + bt) * 256 + sh * 16 + wv * 4 + ul] = h1v;
}

// ---------------- MLP head ----------------
__global__ __launch_bounds__(256, 2) void k_mlp(const float* __restrict__ hfinal,
                                                const float* __restrict__ s,
                                                const float* __restrict__ w1,
                                                const float* __restrict__ b1,
                                                const float* __restrict__ w2,
                                                const float* __restrict__ b2,
                                                const float* __restrict__ wp,
                                                const float* __restrict__ bp,
                                                float* __restrict__ out) {
  __shared__ float feat[257];
  __shared__ float z1[256];
  __shared__ float z2[128];
  const int tid = threadIdx.x, b = blockIdx.x;
  feat[tid] = hfinal[b * 256 + tid];
  if (tid == 0) feat[256] = s[b];
  __syncthreads();
  float a = b1[tid];
  for (int i = 0; i < 257; i++) a += feat[i] * w1[i * 256 + tid];
  z1[tid] = fmaxf(a, 0.f);
  __syncthreads();
  if (tid < 128) {
    float a2 = b2[tid];
    for (int i = 0; i < 256; i++) a2 += z1[i] * w2[i * 128 + tid];
    z2[tid] = fmaxf(a2, 0.f);
  }
  __syncthreads();
  if (tid == 0) {
    float sv = bp[0];
    for (int i = 0; i < 128; i++) sv += z2[i] * wp[i];
    out[b] = fmaxf(sv, 0.f) + log1pf(__expf(-fabsf(sv)));
  }
}

extern "C" void kernel_launch(void* const* d_in, const int* in_sizes, int n_in,
                              void* d_out, int out_size, void* d_ws, size_t ws_size,
                              hipStream_t stream) {
  const float* x = (const float*)d_in[0];
  const float* s = (const float*)d_in[1];
  const float* c1w = (const float*)d_in[2];
  const float* c1b = (const float*)d_in[3];
  const float* bn1g = (const float*)d_in[4];
  const float* bn1b = (const float*)d_in[5];
  const float* c2w = (const float*)d_in[6];
  const float* c2b = (const float*)d_in[7];
  const float* bn2g = (const float*)d_in[8];
  const float* bn2b = (const float*)d_in[9];
  const float* wi0 = (const float*)d_in[10];
  const float* bi0 = (const float*)d_in[11];
  const float* wh0 = (const float*)d_in[12];
  const float* bh0 = (const float*)d_in[13];
  const float* wi1 = (const float*)d_in[14];
  const float* bi1 = (const float*)d_in[15];
  const float* wh1 = (const float*)d_in[16];
  const float* bh1 = (const float*)d_in[17];
  const float* w1 = (const float*)d_in[18];
  const float* b1 = (const float*)d_in[19];
  const float* w2 = (const float*)d_in[20];
  const float* b2 = (const float*)d_in[21];
  const float* wp = (const float*)d_in[22];
  const float* bp = (const float*)d_in[23];

  char* ws = (char*)d_ws;
  float* sc1 = (float*)(ws + OFF_SC1);
  float* sh1 = (float*)(ws + OFF_SH1);
  float* sc2 = (float*)(ws + OFF_SC2);
  float* sh2 = (float*)(ws + OFF_SH2);
  float* b0arr = (float*)(ws + OFF_B0);
  float* b1arr = (float*)(ws + OFF_B1);
  float* part1 = (float*)(ws + OFF_PART1);
  float* part2 = (float*)(ws + OFF_PART2);
  unsigned short* w2f = (unsigned short*)(ws + OFF_W2F);
  unsigned short* wf = (unsigned short*)(ws + OFF_WF);
  unsigned short* seq = (unsigned short*)(ws + OFF_SEQ);
  u64* h0w = (u64*)(ws + OFF_H0W);
  u64* h1w = (u64*)(ws + OFF_H1W);
  float* hf = (float*)(ws + OFF_HF);

  k_init<<<640, 256, 0, stream>>>(h0w);  // zeros h0w (512KB) + h1w (768KB)
  k_conv1<<<256, 256, 0, stream>>>(x, c1w, c1b, part1);
  k_bn1<<<64, 256, 0, stream>>>(part1, bn1g, bn1b, sc1, sh1);
  k_w2frag<<<160, 256, 0, stream>>>(c2w, w2f);
  k_conv2<<<256, 256, 0, stream>>>(x, c1w, c1b, sc1, sh1, w2f, c2b, seq, part2);
  k_bn2<<<128, 256, 0, stream>>>(part2, bn2g, bn2b, sc2, sh2);
  k_bias<<<4, 256, 0, stream>>>(bi0, bh0, wi0, sh2, bi1, bh1, b0arr, b1arr);
  k_wfrag<<<3584, 256, 0, stream>>>(wi0, wh0, wi1, wh1, sc2, wf);
  k_lstm<<<256, 256, 0, stream>>>(seq, wf, b0arr, b1arr, h0w, h1w, hf);
  k_mlp<<<256, 256, 0, stream>>>(hf, s, w1, b1, w2, b2, wp, bp, (float*)d_out);
}

// Round 15
// 840.449 us; speedup vs baseline: 1.6921x; 1.1573x over previous
//
#include <hip/hip_runtime.h>
#include <hip/hip_bf16.h>
#include <hip/hip_fp16.h>
#include <math.h>

#define EPSV 1e-5f

typedef short short8 __attribute__((ext_vector_type(8)));
typedef float f32x4 __attribute__((ext_vector_type(4)));
typedef unsigned long long u64;

#define MFMA(a, b, c) __builtin_amdgcn_mfma_f32_16x16x32_f16(a, b, c, 0, 0, 0)

// ---------------- ws layout (bytes) ----------------
#define OFF_SC1    8192            // 64 f32
#define OFF_SH1    8448
#define OFF_SC2    8704            // 128 f32
#define OFF_SH2    9216
#define OFF_B0     9728            // 1024 f32 = 4096
#define OFF_B1     13824           // 4096
#define OFF_PART1  17920           // 256*64*2*4 = 131072
#define OFF_PART2  148992          // 256*128*2*4 = 262144
#define OFF_W2F    411136          // 40960 f16 = 81920
#define OFF_WF     493056          // 917504 f16 = 1835008
#define OFF_SEQ    2328064         // 256*256*128*2 = 16777216 (f16 [b][t][c])
#define OFF_H0W    19105280        // 2*16*128*16*8 = 524288 (tagged u64 words)
#define OFF_H1W    19629568        // 524288
#define OFF_HF     20153856        // 256*256*4 = 262144 (f32)
// end 20,416,000

__device__ __forceinline__ unsigned short f2h(float f) {
  return __half_as_ushort(__float2half(f));
}
__device__ __forceinline__ float h2f(unsigned short u) {
  return __half2float(__ushort_as_half(u));
}
__device__ __forceinline__ float sigf(float x) { return 1.f / (1.f + __expf(-x)); }
__device__ __forceinline__ float tanhfast(float x) {
  return 1.f - 2.f / (__expf(2.f * x) + 1.f);
}

// ---------------- conv1 + relu + pool4, BN1 partial stats ----------------
__global__ __launch_bounds__(256, 2) void k_conv1(const float* __restrict__ x,
                                                  const float* __restrict__ w1,
                                                  const float* __restrict__ b1,
                                                  float* __restrict__ part1) {
  __shared__ float xs[4104];
  __shared__ float w1s[576];
  __shared__ float b1s[64];
  __shared__ float red[64][4][2];
  const int tid = threadIdx.x, b = blockIdx.x;
  for (int j = tid; j < 4104; j += 256) {
    int p = j - 4;
    xs[j] = (p >= 0 && p < 4096) ? x[b * 4096 + p] : 0.f;
  }
  for (int j = tid; j < 576; j += 256) w1s[j] = w1[j];
  if (tid < 64) b1s[tid] = b1[tid];
  __syncthreads();
  const int c = tid >> 2, lq = tid & 3;
  float wr[9];
#pragma unroll
  for (int k = 0; k < 9; k++) wr[k] = w1s[c * 9 + k];
  const float bb = b1s[c];
  float S = 0.f, SS = 0.f;
  for (int li = 0; li < 256; li++) {
    int l = lq * 256 + li;
    int base = 4 * l;
    float a4 = 0.f;
#pragma unroll
    for (int jj = 0; jj < 4; jj++) {
      float cv = bb;
#pragma unroll
      for (int k = 0; k < 9; k++) cv += xs[base + jj + k] * wr[k];
      a4 += fmaxf(cv, 0.f);
    }
    float y = 0.25f * a4;
    S += y;
    SS += y * y;
  }
  red[c][lq][0] = S;
  red[c][lq][1] = SS;
  __syncthreads();
  if (tid < 64) {
    float s = 0.f, ss = 0.f;
#pragma unroll
    for (int q = 0; q < 4; q++) {
      s += red[tid][q][0];
      ss += red[tid][q][1];
    }
    part1[(b * 64 + tid) * 2 + 0] = s;
    part1[(b * 64 + tid) * 2 + 1] = ss;
  }
}

// ---------------- BN1 finalize ----------------
__global__ void k_bn1(const float* __restrict__ part1, const float* __restrict__ g,
                      const float* __restrict__ bt, float* __restrict__ sc,
                      float* __restrict__ sh) {
  __shared__ float rs[256], rss[256];
  const int c = blockIdx.x, tid = threadIdx.x;
  rs[tid] = part1[(tid * 64 + c) * 2 + 0];
  rss[tid] = part1[(tid * 64 + c) * 2 + 1];
  __syncthreads();
  for (int st = 128; st > 0; st >>= 1) {
    if (tid < st) {
      rs[tid] += rs[tid + st];
      rss[tid] += rss[tid + st];
    }
    __syncthreads();
  }
  if (tid == 0) {
    const float N = 256.f * 1024.f;
    float mean = rs[0] / N;
    float var = rss[0] / N - mean * mean;
    float scale = g[c] * rsqrtf(var + EPSV);
    sc[c] = scale;
    sh[c] = bt[c] - mean * scale;
  }
}

// ---------------- w2 -> MFMA B-fragment layout (f16) ----------------
__global__ void k_w2frag(const float* __restrict__ w2,
                         unsigned short* __restrict__ w2f) {
  int n = blockIdx.x * 256 + threadIdx.x;  // < 40960
  if (n >= 40960) return;
  int e = n & 7, lane = (n >> 3) & 63, ot = (n >> 9) & 7, sc = n >> 12;
  int s = sc >> 1, c2 = sc & 1;
  int o = ot * 16 + (lane & 15);
  int i = c2 * 32 + ((lane >> 4) << 3) + e;
  w2f[n] = f2h(w2[o * 320 + i * 5 + s]);
}

// ---------------- conv2 via MFMA (recomputes conv1+bn1 into LDS y1t) -------
__global__ __launch_bounds__(256, 1) void k_conv2(
    const float* __restrict__ x, const float* __restrict__ w1,
    const float* __restrict__ b1, const float* __restrict__ sc1,
    const float* __restrict__ sh1, const unsigned short* __restrict__ w2f,
    const float* __restrict__ b2, unsigned short* __restrict__ seq,
    float* __restrict__ part2) {
  __shared__ float xs[4104];
  __shared__ unsigned short y1t[1028][66];  // row = l+2, col = i
  __shared__ float w1s[576], b1s[64], s1s[64], h1s[64], b2s[128];
  __shared__ float red[4][2][128];
  const int tid = threadIdx.x, b = blockIdx.x;
  for (int j = tid; j < 4104; j += 256) {
    int p = j - 4;
    xs[j] = (p >= 0 && p < 4096) ? x[b * 4096 + p] : 0.f;
  }
  for (int j = tid; j < 576; j += 256) w1s[j] = w1[j];
  if (tid < 64) {
    b1s[tid] = b1[tid];
    s1s[tid] = sc1[tid];
    h1s[tid] = sh1[tid];
  }
  if (tid < 128) b2s[tid] = b2[tid];
  if (tid < 132) {
    int r4 = tid / 33, c4 = tid % 33;
    int row = (r4 < 2) ? r4 : (1024 + r4);
    ((unsigned int*)&y1t[row][0])[c4] = 0u;
  }
  __syncthreads();
  {
    const int i2 = tid & 31, lg = tid >> 5;
    const int ia = 2 * i2, ib = ia + 1;
    float wra[9], wrb[9];
#pragma unroll
    for (int k = 0; k < 9; k++) {
      wra[k] = w1s[ia * 9 + k];
      wrb[k] = w1s[ib * 9 + k];
    }
    const float bia = b1s[ia], bib = b1s[ib];
    const float sa = s1s[ia], sb = s1s[ib], ha = h1s[ia], hb = h1s[ib];
    for (int j = 0; j < 128; j++) {
      int l = lg * 128 + j;
      float xv[12];
#pragma unroll
      for (int m = 0; m < 12; m++) xv[m] = xs[4 * l + m];
      float aa = 0.f, ab = 0.f;
#pragma unroll
      for (int jj = 0; jj < 4; jj++) {
        float ca = bia, cb = bib;
#pragma unroll
        for (int k = 0; k < 9; k++) {
          float xx = xv[jj + k];
          ca += xx * wra[k];
          cb += xx * wrb[k];
        }
        aa += fmaxf(ca, 0.f);
        ab += fmaxf(cb, 0.f);
      }
      float va = 0.25f * aa * sa + ha;
      float vb = 0.25f * ab * sb + hb;
      unsigned int pk = (unsigned int)f2h(va) | ((unsigned int)f2h(vb) << 16);
      *(unsigned int*)&y1t[l + 2][ia] = pk;
    }
  }
  __syncthreads();
  const int wv = tid >> 6, lane = tid & 63;
  const int colo = lane & 15, rq = lane >> 4;
  float Sa[2][4], SSa[2][4];
#pragma unroll
  for (int a = 0; a < 2; a++)
#pragma unroll
    for (int c = 0; c < 4; c++) {
      Sa[a][c] = 0.f;
      SSa[a][c] = 0.f;
    }
#pragma unroll
  for (int og = 0; og < 2; og++) {
    short8 bf[4][10];
#pragma unroll
    for (int ot = 0; ot < 4; ot++)
#pragma unroll
      for (int sc = 0; sc < 10; sc++)
        bf[ot][sc] = *(const short8*)(w2f + ((sc * 8 + og * 4 + ot) * 64 + lane) * 8);
    for (int ltw = 0; ltw < 16; ltw++) {
      int lt = wv * 16 + ltw;
      int lbase = lt * 16;
      short8 af[10];
#pragma unroll
      for (int s = 0; s < 5; s++)
#pragma unroll
        for (int c2 = 0; c2 < 2; c2++)
          af[s * 2 + c2] =
              *(const short8*)&y1t[lbase + colo + s][c2 * 32 + rq * 8];
#pragma unroll
      for (int ot = 0; ot < 4; ot++) {
        f32x4 acc = {0.f, 0.f, 0.f, 0.f};
#pragma unroll
        for (int sc = 0; sc < 10; sc++)
          acc = MFMA(af[sc], bf[ot][sc], acc);
        int o = (og * 4 + ot) * 16 + colo;
        float bv = b2s[o];
        float s4 = fmaxf(acc[0] + bv, 0.f) + fmaxf(acc[1] + bv, 0.f) +
                   fmaxf(acc[2] + bv, 0.f) + fmaxf(acc[3] + bv, 0.f);
        float y = 0.25f * s4;
        int t_out = lt * 4 + rq;
        seq[(b * 256 + t_out) * 128 + o] = f2h(y);
        Sa[og][ot] += y;
        SSa[og][ot] += y * y;
      }
    }
  }
#pragma unroll
  for (int og = 0; og < 2; og++)
#pragma unroll
    for (int ot = 0; ot < 4; ot++) {
      float sv = Sa[og][ot], ssv = SSa[og][ot];
      sv += __shfl_xor(sv, 16, 64);
      sv += __shfl_xor(sv, 32, 64);
      ssv += __shfl_xor(ssv, 16, 64);
      ssv += __shfl_xor(ssv, 32, 64);
      if (rq == 0) {
        int o = (og * 4 + ot) * 16 + colo;
        red[wv][0][o] = sv;
        red[wv][1][o] = ssv;
      }
    }
  __syncthreads();
  if (tid < 128) {
    float s = red[0][0][tid] + red[1][0][tid] + red[2][0][tid] + red[3][0][tid];
    float ss = red[0][1][tid] + red[1][1][tid] + red[2][1][tid] + red[3][1][tid];
    part2[(b * 128 + tid) * 2 + 0] = s;
    part2[(b * 128 + tid) * 2 + 1] = ss;
  }
}

// ---------------- BN2 finalize ----------------
__global__ void k_bn2(const float* __restrict__ part2, const float* __restrict__ g,
                      const float* __restrict__ bt, float* __restrict__ sc,
                      float* __restrict__ sh) {
  __shared__ float rs[256], rss[256];
  const int o = blockIdx.x, tid = threadIdx.x;
  rs[tid] = part2[(tid * 128 + o) * 2 + 0];
  rss[tid] = part2[(tid * 128 + o) * 2 + 1];
  __syncthreads();
  for (int st = 128; st > 0; st >>= 1) {
    if (tid < st) {
      rs[tid] += rs[tid + st];
      rss[tid] += rss[tid + st];
    }
    __syncthreads();
  }
  if (tid == 0) {
    const float N = 65536.f;
    float mean = rs[0] / N;
    float var = rss[0] / N - mean * mean;
    float scale = g[o] * rsqrtf(var + EPSV);
    sc[o] = scale;
    sh[o] = bt[o] - mean * scale;
  }
}

// ---------------- fold BN2 shift into layer-0 bias ----------------
__global__ void k_bias(const float* __restrict__ bi0, const float* __restrict__ bh0,
                       const float* __restrict__ wi0, const float* __restrict__ sh2,
                       const float* __restrict__ bi1, const float* __restrict__ bh1,
                       float* __restrict__ b0arr, float* __restrict__ b1arr) {
  int g = blockIdx.x * 256 + threadIdx.x;  // < 1024
  float s = bi0[g] + bh0[g];
  for (int k = 0; k < 128; k++) s += sh2[k] * wi0[k * 1024 + g];
  b0arr[g] = s;
  b1arr[g] = bi1[g] + bh1[g];
}

// ---------------- LSTM weights -> A-fragment layout + zero h buffers -------
// blocks 0..3583: wfrag; blocks 0..511 ALSO zero h0w+h1w (1 MB contiguous).
__global__ void k_wfrag(const float* __restrict__ wi0, const float* __restrict__ wh0,
                        const float* __restrict__ wi1, const float* __restrict__ wh1,
                        const float* __restrict__ sc2,
                        unsigned short* __restrict__ wf, u64* __restrict__ hz) {
  if (blockIdx.x < 512) hz[blockIdx.x * 256 + threadIdx.x] = 0ULL;
  const int slot = blockIdx.x / 56;
  const int idx = (blockIdx.x % 56) * 256 + threadIdx.x;  // < 14336
  const int j = idx >> 9, lane = (idx >> 3) & 63, e = idx & 7;
  const int sh = slot >> 2, wv = slot & 3;
  const int m = lane & 15;
  const int gcol = (m & 3) * 256 + sh * 16 + wv * 4 + (m >> 2);
  float v;
  if (j < 12) {
    int k = j * 32 + ((lane >> 4) << 3) + e;
    v = (k < 128) ? sc2[k] * wi0[k * 1024 + gcol] : wh0[(k - 128) * 1024 + gcol];
  } else {
    int k = (j - 12) * 32 + ((lane >> 4) << 3) + e;
    v = (k < 256) ? wi1[k * 1024 + gcol] : wh1[(k - 256) * 1024 + gcol];
  }
  wf[slot * 14336 + idx] = f2h(v);
}

// ---------------- persistent 2-layer LSTM, tagged coalesced exchange -------
// (r7-exact: best measured 720 us across 8 structural variants)
// grid 256 = group gb (blockIdx>>4) x unit-slice sh (blockIdx&15)
// word buffer: [buf][gb][pair p 0..127][batch 0..15] u64
//   word = [tag:16 | h(2p):16 | h(2p+1):16 | 0:16]
__global__ __launch_bounds__(256, 1) void k_lstm(
    const unsigned short* __restrict__ seq, const unsigned short* __restrict__ wf,
    const float* __restrict__ b0arr, const float* __restrict__ b1arr,
    u64* __restrict__ h0w, u64* __restrict__ h1w, float* __restrict__ hfinal) {
  __shared__ unsigned short wlds[4 * 28 * 64 * 8];  // 114688 B
  __shared__ unsigned short hs0[2][16 * 264];       // 16896 B
  __shared__ unsigned short hs1[2][16 * 264];       // 16896 B
  const int tid = threadIdx.x;
  const int gb = blockIdx.x >> 4, sh = blockIdx.x & 15;
  const int b0 = gb * 16;
  const int wv = tid >> 6, lane = tid & 63;
  const int bt = lane & 15;   // batch-local (B-frag col / D col)
  const int ul = lane >> 4;   // unit-local (D row quad / B-frag k-quad)
  const int q8 = ul * 8;

  // ---- stage weight A-fragments into LDS (one copy, fragment-ordered) ----
  {
    const u64* src = (const u64*)(wf + sh * 4 * 14336);
    u64* dst = (u64*)wlds;
    for (int j = tid; j < 14336; j += 256) dst[j] = src[j];
  }
#define LW(j) (*(const short8*)&wlds[(((wv)*28 + (j)) * 64 + lane) * 8])

  f32x4 b0v, b1v;
#pragma unroll
  for (int r = 0; r < 4; r++) {
    int gcol = r * 256 + sh * 16 + wv * 4 + ul;
    b0v[r] = b0arr[gcol];
    b1v[r] = b1arr[gcol];
  }
  float c0 = 0.f, c1 = 0.f, h1v = 0.f;
  const int pidx = (sh * 8 + wv * 2 + (ul >> 1)) * 16 + bt;  // word slot for store
  u64* const st0base = h0w + gb * 2048 + pidx;
  u64* const st1base = h1w + gb * 2048 + pidx;
  __syncthreads();  // weights staged

  // --- prologue: h0(0) = cell(x(0), c=0); store tag 1 into h0w buf0 ---
  {
    const unsigned short* xp = seq + ((b0 + bt) * 256 + 0) * 128 + q8;
    short8 xa0 = *(const short8*)(xp + 0);
    short8 xa1 = *(const short8*)(xp + 32);
    short8 xa2 = *(const short8*)(xp + 64);
    short8 xa3 = *(const short8*)(xp + 96);
    f32x4 acc = b0v;
    acc = MFMA(LW(0), xa0, acc);
    acc = MFMA(LW(1), xa1, acc);
    acc = MFMA(LW(2), xa2, acc);
    acc = MFMA(LW(3), xa3, acc);
    c0 = sigf(acc[1]) * c0 + sigf(acc[0]) * tanhfast(acc[2]);
    float h0v = sigf(acc[3]) * tanhfast(c0);
    unsigned v0 = f2h(h0v);
    unsigned v1 = __shfl_down(v0, 16, 64);
    if ((ul & 1) == 0) {
      u64 w = 1ULL | ((u64)v0 << 16) | ((u64)v1 << 32);
      __hip_atomic_store(st0base, w, __ATOMIC_RELAXED, __HIP_MEMORY_SCOPE_AGENT);
    }
  }

  // --- main loop: interval t computes layer1(t) then layer0(t+1) ---
  for (int t = 0; t < 256; t++) {
    short8 xa0, xa1, xa2, xa3;
    if (t < 255) {
      const unsigned short* xp = seq + ((b0 + bt) * 256 + (t + 1)) * 128 + q8;
      xa0 = *(const short8*)(xp + 0);
      xa1 = *(const short8*)(xp + 32);
      xa2 = *(const short8*)(xp + 64);
      xa3 = *(const short8*)(xp + 96);
    }
    // ---- poll tagged words: h0(t) tag t+1 in buf t&1; h1(t-1) tag t in buf (t+1)&1
    const u64* q0 = h0w + (t & 1) * 32768 + gb * 2048;
    const u64* q1 = h1w + ((t + 1) & 1) * 32768 + gb * 2048;
    const unsigned e0 = (unsigned)(t + 1), e1 = (unsigned)t;
    u64 w0[8], w1[8];
    for (;;) {
      bool ok = true;
#pragma unroll
      for (int u = 0; u < 8; u++) {
        w0[u] = __hip_atomic_load(q0 + u * 256 + tid, __ATOMIC_RELAXED,
                                  __HIP_MEMORY_SCOPE_AGENT);
        w1[u] = __hip_atomic_load(q1 + u * 256 + tid, __ATOMIC_RELAXED,
                                  __HIP_MEMORY_SCOPE_AGENT);
      }
#pragma unroll
      for (int u = 0; u < 8; u++)
        ok = ok & ((unsigned)(unsigned short)w0[u] == e0) &
             ((unsigned)(unsigned short)w1[u] == e1);
      if (__all(ok)) break;
    }
    // ---- unpack to LDS (double-buffered) ----
    const int hb = t & 1;
#pragma unroll
    for (int u = 0; u < 8; u++) {
      int g = u * 256 + tid;
      int bw = g & 15, p = g >> 4;
      *(unsigned*)&hs0[hb][bw * 264 + 2 * p] = (unsigned)(w0[u] >> 16);
      *(unsigned*)&hs1[hb][bw * 264 + 2 * p] = (unsigned)(w1[u] >> 16);
    }
    __syncthreads();  // sole barrier per step
    short8 ha[8], hbf[8];
#pragma unroll
    for (int kk = 0; kk < 8; kk++) {
      ha[kk] = *(const short8*)&hs0[hb][bt * 264 + kk * 32 + q8];
      hbf[kk] = *(const short8*)&hs1[hb][bt * 264 + kk * 32 + q8];
    }
    // layer1(t): W1^T @ [h0(t); h1(t-1)]
    f32x4 acc1a = b1v;
    f32x4 acc1b = {0.f, 0.f, 0.f, 0.f};
#pragma unroll
    for (int kk = 0; kk < 8; kk++) {
      acc1a = MFMA(LW(12 + kk), ha[kk], acc1a);
      acc1b = MFMA(LW(20 + kk), hbf[kk], acc1b);
    }
    // layer0(t+1): W0^T @ [x(t+1); h0(t)]
    f32x4 acc0a = b0v;
    f32x4 acc0b = {0.f, 0.f, 0.f, 0.f};
    if (t < 255) {
      acc0a = MFMA(LW(0), xa0, acc0a);
      acc0b = MFMA(LW(1), xa1, acc0b);
      acc0a = MFMA(LW(2), xa2, acc0a);
      acc0b = MFMA(LW(3), xa3, acc0b);
#pragma unroll
      for (int kk = 0; kk < 8; kk += 2) {
        acc0a = MFMA(LW(4 + kk), ha[kk], acc0a);
        acc0b = MFMA(LW(5 + kk), ha[kk + 1], acc0b);
      }
    }
    // cell1 (lane-local: reg r = gate) -> tagged store tag t+1, buf t&1
    {
      float gi = acc1a[0] + acc1b[0], gf = acc1a[1] + acc1b[1];
      float gg = acc1a[2] + acc1b[2], go = acc1a[3] + acc1b[3];
      c1 = sigf(gf) * c1 + sigf(gi) * tanhfast(gg);
      h1v = sigf(go) * tanhfast(c1);
      unsigned v0 = f2h(h1v);
      unsigned v1 = __shfl_down(v0, 16, 64);
      if ((ul & 1) == 0) {
        u64 w = (u64)(unsigned short)(t + 1) | ((u64)v0 << 16) | ((u64)v1 << 32);
        __hip_atomic_store(st1base + (t & 1) * 32768, w, __ATOMIC_RELAXED,
                           __HIP_MEMORY_SCOPE_AGENT);
      }
    }
    // cell0 -> tagged store tag t+2, buf (t+1)&1
    if (t < 255) {
      c0 = sigf(acc0a[1] + acc0b[1]) * c0 +
           sigf(acc0a[0] + acc0b[0]) * tanhfast(acc0a[2] + acc0b[2]);
      float h0v = sigf(acc0a[3] + acc0b[3]) * tanhfast(c0);
      unsigned v0 = f2h(h0v);
      unsigned v1 = __shfl_down(v0, 16, 64);
      if ((ul & 1) == 0) {
        u64 w = (u64)(unsigned short)(t + 2) | ((u64)v0 << 16) | ((u64)v1 << 32);
        __hip_atomic_store(st0base + ((t + 1) & 1) * 32768, w, __ATOMIC_RELAXED,
                           __HIP_MEMORY_SCOPE_AGENT);
      }
    }
  }
  hfinal[(b0 + bt) * 256 + sh * 16 + wv * 4 + ul] = h1v;
}

// ---------------- MLP head ----------------
__global__ __launch_bounds__(256, 2) void k_mlp(const float* __restrict__ hfinal,
                                                const float* __restrict__ s,
                                                const float* __restrict__ w1,
                                                const float* __restrict__ b1,
                                                const float* __restrict__ w2,
                                                const float* __restrict__ b2,
                                                const float* __restrict__ wp,
                                                const float* __restrict__ bp,
                                                float* __restrict__ out) {
  __shared__ float feat[257];
  __shared__ float z1[256];
  __shared__ float z2[128];
  const int tid = threadIdx.x, b = blockIdx.x;
  feat[tid] = hfinal[b * 256 + tid];
  if (tid == 0) feat[256] = s[b];
  __syncthreads();
  float a = b1[tid];
  for (int i = 0; i < 257; i++) a += feat[i] * w1[i * 256 + tid];
  z1[tid] = fmaxf(a, 0.f);
  __syncthreads();
  if (tid < 128) {
    float a2 = b2[tid];
    for (int i = 0; i < 256; i++) a2 += z1[i] * w2[i * 128 + tid];
    z2[tid] = fmaxf(a2, 0.f);
  }
  __syncthreads();
  if (tid == 0) {
    float sv = bp[0];
    for (int i = 0; i < 128; i++) sv += z2[i] * wp[i];
    out[b] = fmaxf(sv, 0.f) + log1pf(__expf(-fabsf(sv)));
  }
}

extern "C" void kernel_launch(void* const* d_in, const int* in_sizes, int n_in,
                              void* d_out, int out_size, void* d_ws, size_t ws_size,
                              hipStream_t stream) {
  const float* x = (const float*)d_in[0];
  const float* s = (const float*)d_in[1];
  const float* c1w = (const float*)d_in[2];
  const float* c1b = (const float*)d_in[3];
  const float* bn1g = (const float*)d_in[4];
  const float* bn1b = (const float*)d_in[5];
  const float* c2w = (const float*)d_in[6];
  const float* c2b = (const float*)d_in[7];
  const float* bn2g = (const float*)d_in[8];
  const float* bn2b = (const float*)d_in[9];
  const float* wi0 = (const float*)d_in[10];
  const float* bi0 = (const float*)d_in[11];
  const float* wh0 = (const float*)d_in[12];
  const float* bh0 = (const float*)d_in[13];
  const float* wi1 = (const float*)d_in[14];
  const float* bi1 = (const float*)d_in[15];
  const float* wh1 = (const float*)d_in[16];
  const float* bh1 = (const float*)d_in[17];
  const float* w1 = (const float*)d_in[18];
  const float* b1 = (const float*)d_in[19];
  const float* w2 = (const float*)d_in[20];
  const float* b2 = (const float*)d_in[21];
  const float* wp = (const float*)d_in[22];
  const float* bp = (const float*)d_in[23];

  char* ws = (char*)d_ws;
  float* sc1 = (float*)(ws + OFF_SC1);
  float* sh1 = (float*)(ws + OFF_SH1);
  float* sc2 = (float*)(ws + OFF_SC2);
  float* sh2 = (float*)(ws + OFF_SH2);
  float* b0arr = (float*)(ws + OFF_B0);
  float* b1arr = (float*)(ws + OFF_B1);
  float* part1 = (float*)(ws + OFF_PART1);
  float* part2 = (float*)(ws + OFF_PART2);
  unsigned short* w2f = (unsigned short*)(ws + OFF_W2F);
  unsigned short* wf = (unsigned short*)(ws + OFF_WF);
  unsigned short* seq = (unsigned short*)(ws + OFF_SEQ);
  u64* h0w = (u64*)(ws + OFF_H0W);
  u64* h1w = (u64*)(ws + OFF_H1W);
  float* hf = (float*)(ws + OFF_HF);

  k_conv1<<<256, 256, 0, stream>>>(x, c1w, c1b, part1);
  k_bn1<<<64, 256, 0, stream>>>(part1, bn1g, bn1b, sc1, sh1);
  k_w2frag<<<160, 256, 0, stream>>>(c2w, w2f);
  k_conv2<<<256, 256, 0, stream>>>(x, c1w, c1b, sc1, sh1, w2f, c2b, seq, part2);
  k_bn2<<<128, 256, 0, stream>>>(part2, bn2g, bn2b, sc2, sh2);
  k_bias<<<4, 256, 0, stream>>>(bi0, bh0, wi0, sh2, bi1, bh1, b0arr, b1arr);
  k_wfrag<<<3584, 256, 0, stream>>>(wi0, wh0, wi1, wh1, sc2, wf, h0w);
  k_lstm<<<256, 256, 0, stream>>>(seq, wf, b0arr, b1arr, h0w, h1w, hf);
  k_mlp<<<256, 256, 0, stream>>>(hf, s, w1, b1, w2, b2, wp, bp, (float*)d_out);
}